// Round 6
// baseline (205.479 us; speedup 1.0000x reference)
//
#include <hip/hip_runtime.h>

// DynamicRouting (CapsNet) on MI355X — single persistent kernel + memset.
// B=16, I=32, C=8, J=10, D=16, H=W=6 -> DHW=576. num_routing=3 (fixed).
//
// Algebra: c[i,j] broadcasts over C and v is (i,c)-independent, so
//   U[b,i,j,:] = sum_c u_hat[b,i,c,j,:]   (held in REGISTERS, never global)
//   s_r        = sum_i c_r[i,j] U + bias
//   agreement_r[i,j] = sum_b sc_r[b] * G_r[b,i,j],  G_r = sum_dhw U*s_r
// One block per (b,j) (160 blocks x 576 threads = 1 thread/dhw). Each block
// owns its U tile in registers across ALL iterations. Only n1/G partials
// (1.3KB / 40KB per iter) cross the grid. Grid-wide sync via a hand-rolled
// agent-scope barrier (R2 showed cg::grid.sync costs ~80us/sync; this is a
// single atomicAdd + flag poll w/ s_sleep, expected ~1-3us).
// Co-residency: 160 blocks, 74KiB LDS -> 1 block/CU, 256 CUs, exclusive chip.
// Per-phase counter+flag pairs (no sense reversal); memset zeroes them each
// launch (d_ws is re-poisoned 0xAA by the harness before every call).

#define NB   16
#define NI   32
#define NC   8
#define NJ   10
#define ND   16
#define NHW  36
#define NDHW 576
#define NTOT (NB * NJ * NDHW)      // 92160
#define EPSV 1e-7f
#define TPB  576                   // 9 waves; one thread per dhw
#define NBLK 160                   // one block per (b,j)

static __device__ __forceinline__ double wave_sum(double v) {
    #pragma unroll
    for (int off = 32; off > 0; off >>= 1) v += __shfl_down(v, off);
    return v;
}

// block-reduce |sv| over 576 threads -> slot (thread 0 writes, plain store)
static __device__ __forceinline__ void n1_reduce(float sv, double* slot,
                                                 double* nred /*[9]*/) {
    int tid = threadIdx.x;
    double a = wave_sum((double)fabsf(sv));
    if ((tid & 63) == 0) nred[tid >> 6] = a;
    __syncthreads();
    if (tid == 0) {
        double t = nred[0];
        #pragma unroll
        for (int w = 1; w < 9; ++w) t += nred[w];
        *slot = t;
    }
}

// block-reduce Uv[i]*sv over 576 threads for all 32 i -> gslot[i]
static __device__ __forceinline__ void g_reduce(const float* Uv, float sv,
                                                double* gslot,
                                                double (*gred)[32] /*[9][32]*/) {
    int tid = threadIdx.x, w = tid >> 6, lane = tid & 63;
    #pragma unroll
    for (int i = 0; i < NI; ++i) {
        double p = wave_sum((double)Uv[i] * (double)sv);
        if (lane == 0) gred[w][i] = p;
    }
    __syncthreads();
    if (tid < NI) {
        double t = gred[0][tid];
        #pragma unroll
        for (int w2 = 1; w2 < 9; ++w2) t += gred[w2][tid];
        gslot[tid] = t;
    }
}

// grid barrier: cnt/rel are per-phase (memset-zeroed before launch).
// Arrivers' ACQ_REL RMW releases their prior plain stores (after the block
// __syncthreads drained them); last arriver sets rel; spinners acquire it.
static __device__ __forceinline__ void grid_barrier(unsigned* cnt,
                                                    unsigned* rel, int tid) {
    __syncthreads();                       // all block stores issued & drained
    if (tid == 0) {
        __threadfence();                   // device-scope visibility of stores
        unsigned old = __hip_atomic_fetch_add(cnt, 1u, __ATOMIC_ACQ_REL,
                                              __HIP_MEMORY_SCOPE_AGENT);
        if (old == NBLK - 1) {
            __hip_atomic_store(rel, 1u, __ATOMIC_RELEASE,
                               __HIP_MEMORY_SCOPE_AGENT);
        } else {
            while (__hip_atomic_load(rel, __ATOMIC_ACQUIRE,
                                     __HIP_MEMORY_SCOPE_AGENT) == 0u)
                __builtin_amdgcn_s_sleep(8);
        }
    }
    __syncthreads();
}

// rebuild c[:,j] for iteration R (R=1,2) from n1/G partials of iters 0..R-1
static __device__ __forceinline__ void fold_c(
    int R, int j, int tid,
    const double* __restrict__ n1p, const double* __restrict__ Gp,
    double (*sc_sh)[NB], float* bij_sh, float* c_sh)
{
    if (tid < R * NB) {
        int rr = tid / NB, bb = tid - rr * NB;
        double n1 = 0.0;
        #pragma unroll
        for (int jj = 0; jj < NJ; ++jj) n1 += n1p[rr * (NB * NJ) + bb * NJ + jj];
        double nsq = n1 * n1;
        sc_sh[rr][bb] = (nsq / (1.0 + nsq)) / (n1 + (double)EPSV);
    }
    __syncthreads();
    if (tid < NI * NJ) {
        int i = tid / NJ, jj = tid - i * NJ;
        double a = 0.0;
        for (int rr = 0; rr < R; ++rr)
            #pragma unroll
            for (int bb = 0; bb < NB; ++bb)
                a += sc_sh[rr][bb] *
                     Gp[(size_t)(rr * NB + bb) * NJ * NI + (size_t)jj * NI + i];
        bij_sh[tid] = (float)a;
    }
    __syncthreads();
    if (tid < NI) {
        float m = -1e30f;
        #pragma unroll
        for (int jj = 0; jj < NJ; ++jj) m = fmaxf(m, bij_sh[tid * NJ + jj]);
        float sum = 0.f;
        #pragma unroll
        for (int jj = 0; jj < NJ; ++jj) sum += expf(bij_sh[tid * NJ + jj] - m);
        c_sh[tid] = expf(bij_sh[tid * NJ + j] - m) / sum;
    }
    __syncthreads();
}

// ---------------------------------------------------------------------------
// The whole pipeline. bar[0..2]=cnt per phase, bar[3..5]=release per phase.
// ---------------------------------------------------------------------------
__global__ __launch_bounds__(TPB) void mega_kernel(
    const float4* __restrict__ uh4, const float* __restrict__ bias,
    double* __restrict__ n1p, double* __restrict__ Gp,
    unsigned* __restrict__ bar, float* __restrict__ out)
{
    __shared__ float4  Utile4[NI * 144];   // 73728 B transpose buffer
    __shared__ double  nred[9];
    __shared__ double  gred[9][32];
    __shared__ double  sc_sh[2][NB];
    __shared__ float   bij_sh[NI * NJ];
    __shared__ float   c_sh[NI];

    const int blk = blockIdx.x;            // b*NJ + j
    const int b = blk / NJ, j = blk - b * NJ;
    const int tid = threadIdx.x;           // dhw

    // ---- phase 0: channel-reduce u_hat into LDS (float4, 8/thread) ----
    // u_hat float4 index: ((b*NI+i)*NC + c)*1440 + j*144 + f4
    #pragma unroll
    for (int g = 0; g < 8; ++g) {
        int lin = g * TPB + tid;           // < 4608 = 32*144
        int i = lin / 144, f4 = lin - i * 144;
        const float4* p = uh4 + ((size_t)(b * NI + i) * NC) * 1440 + j * 144 + f4;
        float4 acc = make_float4(0.f, 0.f, 0.f, 0.f);
        #pragma unroll
        for (int c = 0; c < NC; ++c) {
            float4 v = p[(size_t)c * 1440];
            acc.x += v.x; acc.y += v.y; acc.z += v.z; acc.w += v.w;
        }
        Utile4[lin] = acc;
    }
    __syncthreads();

    // transpose into registers: this thread's dhw column, all i
    const float* Utile = (const float*)Utile4;
    float Uv[NI];
    #pragma unroll
    for (int i = 0; i < NI; ++i) Uv[i] = Utile[i * NDHW + tid];
    const float bias_v = bias[j * ND + tid / NHW];

    // ---- iteration 0: c = 0.1 exactly (softmax of zeros) ----
    float sv = bias_v;
    #pragma unroll
    for (int i = 0; i < NI; ++i) sv += 0.1f * Uv[i];
    n1_reduce(sv, &n1p[blk], nred);
    g_reduce(Uv, sv, &Gp[(size_t)blk * NI], gred);
    grid_barrier(&bar[0], &bar[3], tid);

    // ---- iteration 1 ----
    fold_c(1, j, tid, n1p, Gp, sc_sh, bij_sh, c_sh);
    sv = bias_v;
    #pragma unroll
    for (int i = 0; i < NI; ++i) sv += c_sh[i] * Uv[i];
    n1_reduce(sv, &n1p[NB * NJ + blk], nred);
    g_reduce(Uv, sv, &Gp[(size_t)(NB * NJ + blk) * NI], gred);
    grid_barrier(&bar[1], &bar[4], tid);

    // ---- iteration 2 ----
    fold_c(2, j, tid, n1p, Gp, sc_sh, bij_sh, c_sh);
    sv = bias_v;
    #pragma unroll
    for (int i = 0; i < NI; ++i) sv += c_sh[i] * Uv[i];
    n1_reduce(sv, &n1p[2 * NB * NJ + blk], nred);
    grid_barrier(&bar[2], &bar[5], tid);

    // ---- v = (n1^2/(1+n1^2)) * (s/(n1+eps)) ----
    double n1 = 0.0;
    #pragma unroll
    for (int jj = 0; jj < NJ; ++jj) n1 += n1p[2 * NB * NJ + b * NJ + jj];
    float n1f = (float)n1;
    float nsq = n1f * n1f;
    out[blk * NDHW + tid] = (nsq / (1.f + nsq)) * (sv / (n1f + EPSV));
}

extern "C" void kernel_launch(void* const* d_in, const int* in_sizes, int n_in,
                              void* d_out, int out_size, void* d_ws, size_t ws_size,
                              hipStream_t stream)
{
    const float* u_hat = (const float*)d_in[0];
    const float* bias  = (const float*)d_in[1];
    // d_in[2] = num_routing, fixed at 3 by the problem.

    unsigned* bar = (unsigned*)d_ws;                 // 6 u32 (cnt[3], rel[3])
    double*   n1p = (double*)((char*)d_ws + 32);     // 3*160 doubles
    double*   Gp  = n1p + 3 * NB * NJ;               // 2*160*32 doubles
    float*    out = (float*)d_out;

    hipMemsetAsync(bar, 0, 6 * sizeof(unsigned), stream);
    mega_kernel<<<NBLK, TPB, 0, stream>>>(
        (const float4*)u_hat, bias, n1p, Gp, bar, out);
}